// Round 1
// baseline (288.568 us; speedup 1.0000x reference)
//
#include <hip/hip_runtime.h>
#include <hip/hip_bf16.h>

#define NB 262144   // batch
#define KD 512      // in_dim
#define ED 10000    // embed_dim

typedef __attribute__((ext_vector_type(8))) short s8v;
typedef __attribute__((ext_vector_type(4))) float f4v;

typedef __attribute__((address_space(1))) const unsigned int gu32_t;
typedef __attribute__((address_space(3))) unsigned int lu32_t;

__device__ __forceinline__ short f2bf(float f) {
  union { __hip_bfloat16 h; short s; } u;
  u.h = __float2bfloat16(f);
  return u.s;
}

// ---------------- prep: pack [W_logvar; W_mean] -> bf16 [256][512] ----------------
__global__ void prep_w(const float* __restrict__ Wlv, const float* __restrict__ Wmu,
                       unsigned short* __restrict__ wbf) {
  int i = blockIdx.x * 256 + threadIdx.x;          // [0, 131072)
  int row = i >> 9, col = i & 511;
  float v = (row < 128) ? Wlv[(row << 9) | col] : Wmu[((row - 128) << 9) | col];
  union { __hip_bfloat16 h; unsigned short s; } u;
  u.h = __float2bfloat16(v);
  wbf[i] = u.s;
}

// ---------------- prep: embT[v][l] = W_embed[l][v] + b_embed[l] ----------------
__global__ void prep_embT(const float* __restrict__ We, const float* __restrict__ be,
                          float* __restrict__ embT) {
  int v = blockIdx.x;            // [0, 10000)
  int l = threadIdx.x;           // [0, 128)
  embT[(size_t)v * 128 + l] = We[(size_t)l * ED + v] + be[l];
}

// ---------------- main GEMM: logvar & mean heads ----------------
// x fp32 [B][512]; wbf bf16 [256][512] (rows 0-127 logvar, 128-255 mean)
// LDS: x tile fp32 [128][64] swizzled (32KB) + W tile bf16 [256][64] swizzled (32KB)
__global__ __launch_bounds__(512, 4) void gemm_heads(
    const float* __restrict__ x, const unsigned short* __restrict__ wbf,
    const float* __restrict__ blv, const float* __restrict__ bmu,
    float* __restrict__ out) {
  __shared__ char lds[65536];
  const int tid  = threadIdx.x;
  const int lane = tid & 63;
  const int wid  = tid >> 6;
  const int gm   = blockIdx.x << 7;
  const int wm   = wid >> 2;   // 0..1  (M)
  const int wn   = wid & 3;    // 0..3  (N)

  // staging: linear LDS dest (global_load_lds), inverse-swizzled global source
  unsigned xoff[4], woff[4], xdst[4], wdst[4];
#pragma unroll
  for (int c = 0; c < 4; ++c) {
    int o16 = (wid << 8) + (c << 6) + lane;        // 16B-chunk index
    {  // x: 16 chunks per 256B row; swizzle byte^=((row&7)<<5) -> chunk^=((row&7)<<1)
      int row = o16 >> 4, q16 = o16 & 15;
      int kb16 = q16 ^ ((row & 7) << 1);
      xoff[c] = (unsigned)(row << 9) + (unsigned)(kb16 << 2);     // float elements
      xdst[c] = (unsigned)(((wid << 8) + (c << 6)) << 4);
    }
    {  // W: 8 chunks per 128B row; swizzle byte^=((row&7)<<4) -> chunk^=(row&7)
      int row = o16 >> 3, q16 = o16 & 7;
      int kb16 = q16 ^ (row & 7);
      woff[c] = (unsigned)(row << 9) + (unsigned)(kb16 << 3);     // bf16 elements
      wdst[c] = 32768u + (unsigned)(((wid << 8) + (c << 6)) << 4);
    }
  }
  const float* xblk = x + ((size_t)gm << 9);

  // fragment-read LDS offsets at ks=0; ks toggles bit7 (A) / bit6 (B)
  unsigned offA[4], offB[4];
#pragma unroll
  for (int t = 0; t < 4; ++t) {
    { int row = (wm << 6) + (t << 4) + (lane & 15);
      int kb  = (lane >> 4) << 5;                 // 8 floats -> 32B units
      offA[t] = (unsigned)(row << 8) + (unsigned)(kb ^ ((row & 7) << 5)); }
    { int row = (wn << 6) + (t << 4) + (lane & 15);
      int kb  = (lane >> 4) << 4;                 // 8 bf16 -> 16B units
      offB[t] = 32768u + (unsigned)(row << 7) + (unsigned)(kb ^ ((row & 7) << 4)); }
  }

  f4v acc[4][4];
#pragma unroll
  for (int i = 0; i < 4; ++i)
#pragma unroll
    for (int j = 0; j < 4; ++j) acc[i][j] = (f4v)0.f;

  for (int ko = 0; ko < 8; ++ko) {
    const int ke = ko << 6;   // element offset into K
#pragma unroll
    for (int c = 0; c < 4; ++c) {
      __builtin_amdgcn_global_load_lds((const gu32_t*)(xblk + xoff[c] + ke),
                                       (lu32_t*)(lds + xdst[c]), 16, 0, 0);
      __builtin_amdgcn_global_load_lds((const gu32_t*)(wbf + woff[c] + ke),
                                       (lu32_t*)(lds + wdst[c]), 16, 0, 0);
    }
    __syncthreads();
#pragma unroll
    for (int ks = 0; ks < 2; ++ks) {
      s8v bfr[4];
#pragma unroll
      for (int nt = 0; nt < 4; ++nt)
        bfr[nt] = *(const s8v*)(lds + (offB[nt] ^ (ks << 6)));
#pragma unroll
      for (int mt = 0; mt < 4; ++mt) {
        const char* pa = lds + (offA[mt] ^ (ks << 7));
        float4 a0 = *(const float4*)(pa);
        float4 a1 = *(const float4*)(pa + 16);
        s8v af;
        af[0] = f2bf(a0.x); af[1] = f2bf(a0.y); af[2] = f2bf(a0.z); af[3] = f2bf(a0.w);
        af[4] = f2bf(a1.x); af[5] = f2bf(a1.y); af[6] = f2bf(a1.z); af[7] = f2bf(a1.w);
#pragma unroll
        for (int nt = 0; nt < 4; ++nt)
          acc[mt][nt] = __builtin_amdgcn_mfma_f32_16x16x32_bf16(af, bfr[nt], acc[mt][nt], 0, 0, 0);
      }
    }
    __syncthreads();
  }

  // epilogue: C/D layout col=lane&15, row=(lane>>4)*4+r
  const int col16 = lane & 15;
  const int rsub  = (lane >> 4) << 2;
#pragma unroll
  for (int nt = 0; nt < 4; ++nt) {
    int col = (wn << 6) + (nt << 4) + col16;
    float bias = (col < 128) ? blv[col] : bmu[col - 128];
    float* ob = (col < 128) ? (out + col)
                            : (out + ((size_t)NB << 7) + (col - 128));
#pragma unroll
    for (int mt = 0; mt < 4; ++mt) {
      int row0 = gm + (wm << 6) + (mt << 4) + rsub;
#pragma unroll
      for (int r = 0; r < 4; ++r)
        ob[(size_t)(row0 + r) << 7] = acc[mt][nt][r] + bias;
    }
  }
}

// ---------------- embed: coalesced row gather from embT ----------------
__global__ void embed_fast(const int* __restrict__ y, const float* __restrict__ embT,
                           float* __restrict__ out3) {
  unsigned t = blockIdx.x * 256 + threadIdx.x;   // [0, NB*32)
  int b  = t >> 5;
  int l4 = (t & 31) << 2;
  int v  = y[b];
  float4 s = *(const float4*)(embT + (size_t)v * 128 + l4);
  *(float4*)(out3 + ((size_t)b << 7) + l4) = s;
}

// ---------------- fallbacks (only if ws_size too small) ----------------
__global__ void gemm_naive(const float* __restrict__ x,
                           const float* __restrict__ Wlv, const float* __restrict__ blv,
                           const float* __restrict__ Wmu, const float* __restrict__ bmu,
                           float* __restrict__ out) {
  __shared__ float xr[512];
  int b = blockIdx.x;
  for (int i = threadIdx.x; i < 512; i += 256) xr[i] = x[(size_t)b * 512 + i];
  __syncthreads();
  int c = threadIdx.x;
  const float* w = (c < 128) ? (Wlv + c * 512) : (Wmu + (c - 128) * 512);
  float s = 0.f;
  for (int k = 0; k < 512; ++k) s += xr[k] * w[k];
  s += (c < 128) ? blv[c] : bmu[c - 128];
  float* o = (c < 128) ? (out + (size_t)b * 128 + c)
                       : (out + ((size_t)NB << 7) + (size_t)b * 128 + (c - 128));
  *o = s;
}

__global__ void embed_direct(const int* __restrict__ y, const float* __restrict__ We,
                             const float* __restrict__ be, float* __restrict__ out3) {
  size_t t = (size_t)blockIdx.x * 256 + threadIdx.x;
  int b = (int)(t >> 7), l = (int)(t & 127);
  out3[t] = We[(size_t)l * ED + y[b]] + be[l];
}

extern "C" void kernel_launch(void* const* d_in, const int* in_sizes, int n_in,
                              void* d_out, int out_size, void* d_ws, size_t ws_size,
                              hipStream_t stream) {
  const float* x   = (const float*)d_in[0];
  const int*   y   = (const int*)d_in[1];
  const float* Wlv = (const float*)d_in[2];
  const float* blv = (const float*)d_in[3];
  const float* Wmu = (const float*)d_in[4];
  const float* bmu = (const float*)d_in[5];
  const float* We  = (const float*)d_in[6];
  const float* be  = (const float*)d_in[7];
  float* out  = (float*)d_out;
  float* out3 = out + ((size_t)NB << 8);   // after logvar+mean (2*B*128)

  const size_t needW = 256 * 512 * sizeof(unsigned short);          // 256 KB
  const size_t needE = needW + (size_t)ED * 128 * sizeof(float);    // + 5.12 MB
  unsigned short* wbf = (unsigned short*)d_ws;
  float* embT = (float*)((char*)d_ws + needW);

  if (ws_size >= needW) {
    prep_w<<<512, 256, 0, stream>>>(Wlv, Wmu, wbf);
    gemm_heads<<<NB / 128, 512, 0, stream>>>(x, wbf, blv, bmu, out);
  } else {
    gemm_naive<<<NB, 256, 0, stream>>>(x, Wlv, blv, Wmu, bmu, out);
  }

  if (ws_size >= needE) {
    prep_embT<<<ED, 128, 0, stream>>>(We, be, embT);
    embed_fast<<<NB * 32 / 256, 256, 0, stream>>>(y, embT, out3);
  } else {
    embed_direct<<<NB * 128 / 256, 256, 0, stream>>>(y, We, be, out3);
  }
}